// Round 7
// baseline (210.474 us; speedup 1.0000x reference)
//
#include <hip/hip_runtime.h>
#include <hip/hip_bf16.h>
#include <math.h>

#define BSZ 512
#define FDIM 512
#define NK 32
#define DD 16
#define NDIM (NK*DD)      // 512
#define OUTW (FDIM + NK)  // 544
#define NBLK 256
#define NTHR 1024

typedef __attribute__((ext_vector_type(8))) short short8;   // bf16x8 frag
typedef __attribute__((ext_vector_type(4))) float float4v;  // C/D frag

static __device__ __forceinline__ short f2bf(float f) {
  return (short)__builtin_bit_cast(unsigned short, __float2bfloat16(f));
}

// ---------------------------------------------------------------------------
// Fused kernel. grid 256 x 1024 (16 waves). 256 blocks x <=128 VGPR (forced
// by 1024-thr block) => ALL blocks co-resident (capacity >= 2/CU): the
// producer/consumer spin below is deadlock-free by construction.
//
// Phase 0 [drain-fighting read burst]: every thread reads ONE coalesced
//   float2 covering x+T exactly once chip-wide (32768 lines in flight at
//   t=0), sunk through LDS + barrier so the kernel actually WAITS for them
//   (R6's touch raced its consumers and was useless). After this, x/T are
//   L2/L3-warm for everyone.
// Phase 1 [producer]: block b=(rg=b>>3, cgg=b&7) computes m tile
//   rows 16rg..+16 x cols 64cgg..+64 via bf16 MFMA (wave = (ct,kc): 16-col
//   subtile x 128-K chunk; batched 40 global loads, now cache-warm), LDS
//   K-reduce, coalesced m store; then threadfence + agent-release counter
//   bump on ctr[cgg]. Also copies x -> out[:, :512] (L2-warm).
// Phase 2 [consumer]: block b=(ig=b>>5, k=b&31) acquire-spins until
//   ctr[k>>2]==32 (its 32 producers), stages m[:, 16k..+16] (32 KB) to LDS,
//   computes feats[ig*64..+64, k] = sum_j exp(-L1) with lane<->i,
//   wave<->32-j chunk: per j, 4 uniform ds_read_b128 (broadcast) + 32 VALU
//   + exp. Wave partials reduced in LDS -> DIRECT stores (no atomics, no
//   feats pre-zero). Early-k consumers run while late producers still wait
//   on reads -> dist work overlaps residual stalls.
// ---------------------------------------------------------------------------
__global__ __launch_bounds__(1024) void k_fused(
    const float* __restrict__ x, const float* __restrict__ T,
    float* __restrict__ m, unsigned* __restrict__ ctr,
    float* __restrict__ out) {
  __shared__ float Bs[512 * DD];   // 32 KB: phase1 K-reduce, phase2 m-stage
  __shared__ float red2[NTHR];     // 4 KB: phase0 sink, phase2 reduce

  const int t = threadIdx.x;
  const int b = blockIdx.x;

  // ---------------- phase 0: exact-1x chip-wide read burst ----------------
  {
    const int g = b * NTHR + t;               // 0..262143
    const float2* xx = (const float2*)x;      // 131072 float2
    const float2* tt = (const float2*)T;
    const float2 v = (g < 131072) ? xx[g] : tt[g - 131072];
    red2[t] = v.x + v.y;                      // ds_write forces the wait
  }
  __syncthreads();

  // ---------------- phase 1: producer (m tile via MFMA) -------------------
  const int rg = b >> 3, cgg = b & 7;
  const int r0 = rg * 16, c0 = cgg * 64;
  const int w  = t >> 6;                      // wave 0..15
  const int ct = w & 3, kc = w >> 2;          // col subtile / K chunk
  const int lane = t & 63, mi = lane & 15, q = lane >> 4;

  {
    const float* __restrict__ xa =
        x + (size_t)(r0 + mi) * FDIM + 128 * kc + 8 * q;
    const float* __restrict__ tb =
        T + (size_t)(128 * kc + 8 * q) * NDIM + c0 + 16 * ct + mi;
    float4 A[8];
    float  Bv[32];
#pragma unroll
    for (int j = 0; j < 4; ++j) {
      A[2 * j]     = *(const float4*)(xa + 32 * j);
      A[2 * j + 1] = *(const float4*)(xa + 32 * j + 4);
    }
#pragma unroll
    for (int j = 0; j < 4; ++j)
#pragma unroll
      for (int i = 0; i < 8; ++i)
        Bv[8 * j + i] = tb[(size_t)(32 * j + i) * NDIM];

    float4v acc = {0.f, 0.f, 0.f, 0.f};
#pragma unroll
    for (int j = 0; j < 4; ++j) {
      short8 af, bf;
      af[0] = f2bf(A[2*j].x);   af[1] = f2bf(A[2*j].y);
      af[2] = f2bf(A[2*j].z);   af[3] = f2bf(A[2*j].w);
      af[4] = f2bf(A[2*j+1].x); af[5] = f2bf(A[2*j+1].y);
      af[6] = f2bf(A[2*j+1].z); af[7] = f2bf(A[2*j+1].w);
#pragma unroll
      for (int i = 0; i < 8; ++i) bf[i] = f2bf(Bv[8 * j + i]);
      acc = __builtin_amdgcn_mfma_f32_16x16x32_bf16(af, bf, acc, 0, 0, 0);
    }
    // stash wave partials: Bs as red1[kc][ct][row16][col16]
#pragma unroll
    for (int r = 0; r < 4; ++r)
      Bs[(((kc * 4 + ct) * 16) + (q * 4 + r)) * 16 + mi] = acc[r];
  }
  __syncthreads();
  {  // combine 4 K-chunks, store tile (16x64), coalesced
    const int row = t >> 6, col = t & 63;
    float s = 0.f;
#pragma unroll
    for (int k2 = 0; k2 < 4; ++k2)
      s += Bs[(((k2 * 4 + (col >> 4)) * 16) + row) * 16 + (col & 15)];
    m[(size_t)(r0 + row) * NDIM + c0 + col] = s;
  }
  if (t < 256) {  // x -> out[:, :512]: 256 float4/block, L2-warm
    const int idx = b * 256 + t;
    const int orow = idx >> 7, c4 = idx & 127;
    *(float4*)(out + (size_t)orow * OUTW + c4 * 4) =
        *(const float4*)(x + (size_t)orow * FDIM + c4 * 4);
  }
  __threadfence();
  __syncthreads();
  if (t == 0)
    __hip_atomic_fetch_add(&ctr[cgg], 1u, __ATOMIC_RELEASE,
                           __HIP_MEMORY_SCOPE_AGENT);

  // ---------------- phase 2: consumer (dist for (ig, k)) ------------------
  const int ig = b >> 5, kk = b & 31;
  if (t == 0) {
    while (__hip_atomic_load(&ctr[kk >> 2], __ATOMIC_ACQUIRE,
                             __HIP_MEMORY_SCOPE_AGENT) < 32u)
      __builtin_amdgcn_s_sleep(2);
  }
  __syncthreads();
  __threadfence();

  // stage m[:, 16k..+16] -> Bs[512][16]; 2048 float4, 2 per thread
#pragma unroll
  for (int it = 0; it < 2; ++it) {
    const int idx = it * NTHR + t;           // 0..2047
    const int row = idx >> 2, part = idx & 3;
    *(float4*)&Bs[row * DD + part * 4] =
        *(const float4*)(m + (size_t)row * NDIM + kk * DD + part * 4);
  }
  __syncthreads();

  float a[DD];
  {  // per-lane A row (one-time; bank conflicts here are negligible)
    const float4* ap = (const float4*)&Bs[(ig * 64 + lane) * DD];
    const float4 A0 = ap[0], A1 = ap[1], A2 = ap[2], A3 = ap[3];
    a[0]=A0.x; a[1]=A0.y; a[2]=A0.z;  a[3]=A0.w;
    a[4]=A1.x; a[5]=A1.y; a[6]=A1.z;  a[7]=A1.w;
    a[8]=A2.x; a[9]=A2.y; a[10]=A2.z; a[11]=A2.w;
    a[12]=A3.x;a[13]=A3.y;a[14]=A3.z; a[15]=A3.w;
  }

  float f = 0.f;
  const int j0 = w * 32;
#pragma unroll 4
  for (int j = 0; j < 32; ++j) {
    const float4* bp = (const float4*)&Bs[(j0 + j) * DD];  // uniform/bcast
    const float4 b0 = bp[0], b1 = bp[1], b2 = bp[2], b3 = bp[3];
    float d =
        fabsf(a[0]  - b0.x) + fabsf(a[1]  - b0.y) +
        fabsf(a[2]  - b0.z) + fabsf(a[3]  - b0.w) +
        fabsf(a[4]  - b1.x) + fabsf(a[5]  - b1.y) +
        fabsf(a[6]  - b1.z) + fabsf(a[7]  - b1.w) +
        fabsf(a[8]  - b2.x) + fabsf(a[9]  - b2.y) +
        fabsf(a[10] - b2.z) + fabsf(a[11] - b2.w) +
        fabsf(a[12] - b3.x) + fabsf(a[13] - b3.y) +
        fabsf(a[14] - b3.z) + fabsf(a[15] - b3.w);
    f += __expf(-d);
  }
  red2[w * 64 + lane] = f;
  __syncthreads();
  if (t < 64) {
    float s = 0.f;
#pragma unroll
    for (int ww = 0; ww < 16; ++ww) s += red2[ww * 64 + t];
    out[(size_t)(ig * 64 + t) * OUTW + FDIM + kk] = s;  // exclusive, direct
  }
}

extern "C" void kernel_launch(void* const* d_in, const int* in_sizes, int n_in,
                              void* d_out, int out_size, void* d_ws,
                              size_t ws_size, hipStream_t stream) {
  (void)in_sizes; (void)n_in; (void)out_size; (void)ws_size;
  const float* x = (const float*)d_in[0];
  const float* T = (const float*)d_in[1];
  float* out = (float*)d_out;
  float* m   = (float*)d_ws;                       // 1 MB
  unsigned* ctr = (unsigned*)((char*)d_ws + (size_t)BSZ * NDIM * 4);

  hipMemsetAsync(ctr, 0, 8 * sizeof(unsigned), stream);  // capture-safe node
  hipLaunchKernelGGL(k_fused, dim3(NBLK), dim3(NTHR), 0, stream,
                     x, T, m, ctr, out);
}

// Round 9
// 74.250 us; speedup vs baseline: 2.8347x; 2.8347x over previous
//
#include <hip/hip_runtime.h>
#include <hip/hip_bf16.h>
#include <math.h>

#define BSZ 512
#define FDIM 512
#define NK 32
#define DD 16
#define NDIM (NK*DD)      // 512
#define OUTW (FDIM + NK)  // 544

typedef __attribute__((ext_vector_type(8))) short short8;   // bf16x8 frag
typedef __attribute__((ext_vector_type(4))) float float4v;  // C/D frag

static __device__ __forceinline__ unsigned short f2bfu(float f) {
  return __builtin_bit_cast(unsigned short, __float2bfloat16(f));
}

// ---------------------------------------------------------------------------
// Kernel 0 (k_prep): the ONLY kernel that touches cold HBM. Streams x and T
// exactly once, perfectly coalesced (the drain-gated window rate-limits cold
// reads to ~80-190 GB/s regardless of structure -- R3/R4/R5 evidence -- so
// minimize bytes and maximize MLP). Produces:
//   xbf[512][512] bf16 row-major      (A-fragments: 16B/load)
//   tbf[512][512] bf16 = T TRANSPOSED (B-fragments: 16B/load, Tt[n][k])
//   out[:, :512] = x   (free: same registers as the x read)
//   out[:, 512:544] = 0 (for k_dist's atomicAdd)
// grid 128 x 256: blocks 0..63 = T 64x64 tiles via LDS transpose (coalesced
// read AND write); blocks 64..127 = x convert + out-copy + feats-zero.
// ---------------------------------------------------------------------------
__global__ __launch_bounds__(256) void k_prep(
    const float* __restrict__ x, const float* __restrict__ T,
    unsigned short* __restrict__ xbf, unsigned short* __restrict__ tbf,
    float* __restrict__ out) {
  const int t = threadIdx.x, b = blockIdx.x;
  if (b < 64) {
    __shared__ unsigned short lt[64][65];  // +1 pad: transpose bounce
    const int tr = b >> 3, tc = b & 7;     // 64x64 tile of T
    const float4* T4 = (const float4*)T;   // T row = 128 float4
#pragma unroll
    for (int qi = 0; qi < 4; ++qi) {
      const int idx = qi * 256 + t;        // 0..1023
      const int rr = idx >> 4, c4 = idx & 15;
      const float4 v = T4[(size_t)(tr * 64 + rr) * 128 + tc * 16 + c4];
      lt[c4 * 4 + 0][rr] = f2bfu(v.x);
      lt[c4 * 4 + 1][rr] = f2bfu(v.y);
      lt[c4 * 4 + 2][rr] = f2bfu(v.z);
      lt[c4 * 4 + 3][rr] = f2bfu(v.w);
    }
    __syncthreads();
#pragma unroll
    for (int qi = 0; qi < 8; ++qi) {
      const int idx = qi * 256 + t;        // 0..2047 (ushort2 units)
      const int cl = idx >> 5, sg = idx & 31;
      ushort2 p;
      p.x = lt[cl][sg * 2];
      p.y = lt[cl][sg * 2 + 1];
      *(ushort2*)(tbf + (size_t)(tc * 64 + cl) * 512 + tr * 64 + sg * 2) = p;
    }
  } else {
    const int bb = b - 64;
    const float4* x4 = (const float4*)x;   // 65536 float4
#pragma unroll
    for (int qi = 0; qi < 4; ++qi) {
      const int i = bb * 1024 + qi * 256 + t;   // 0..65535, coalesced
      const float4 v = x4[i];
      const int orow = i >> 7, c4 = i & 127;
      *(float4*)(out + (size_t)orow * OUTW + c4 * 4) = v;  // x -> out
      ushort4 u;
      u.x = f2bfu(v.x); u.y = f2bfu(v.y); u.z = f2bfu(v.z); u.w = f2bfu(v.w);
      *(ushort4*)(xbf + (size_t)i * 4) = u;                // bf16 x
    }
    const int idx2 = bb * 256 + t;          // 0..16383: zero feats cols
    out[(size_t)(idx2 >> 5) * OUTW + FDIM + (idx2 & 31)] = 0.f;
  }
}

// ---------------------------------------------------------------------------
// Kernel 1 (k_gemm): m = x @ T via bf16 MFMA, reading ONLY the just-written
// bf16 ws buffers (L2/IC-hot -> not drain-gated). grid 1024 = 32rg x 32cg
// (16x16 tile), 256 thr = 4 waves (wave = 128-K chunk). Per wave: 4 MFMAs,
// each fed by exactly 2 dwordx4 loads (A from xbf row, B from Tt row --
// the transpose turned 32 scalar B-loads into 4 vector loads). 4KB LDS
// K-reduce, coalesced fp32 m store. Layouts HW-verified (m89):
// A[m=lane&15][k=8q+i], C/D col=lane&15 row=4q+reg.
// ---------------------------------------------------------------------------
__global__ __launch_bounds__(256, 4) void k_gemm(
    const unsigned short* __restrict__ xbf,
    const unsigned short* __restrict__ tbf, float* __restrict__ m) {
  const int t  = threadIdx.x;
  const int b  = blockIdx.x;
  const int rg = b >> 5, cg = b & 31;
  const int r0 = rg * 16, c0 = cg * 16;
  const int lane = t & 63;
  const int w    = __builtin_amdgcn_readfirstlane(t >> 6);  // K-chunk 0..3
  const int mi   = lane & 15;
  const int q    = lane >> 4;

  const unsigned short* __restrict__ xa =
      xbf + (size_t)(r0 + mi) * FDIM + 128 * w + 8 * q;
  const unsigned short* __restrict__ tb =
      tbf + (size_t)(c0 + mi) * FDIM + 128 * w + 8 * q;

  short8 af[4], bf[4];
#pragma unroll
  for (int j = 0; j < 4; ++j) {          // batch all 8 loads before use
    af[j] = *(const short8*)(xa + 32 * j);
    bf[j] = *(const short8*)(tb + 32 * j);
  }
  float4v acc = {0.f, 0.f, 0.f, 0.f};
#pragma unroll
  for (int j = 0; j < 4; ++j)
    acc = __builtin_amdgcn_mfma_f32_16x16x32_bf16(af[j], bf[j], acc, 0, 0, 0);

  __shared__ float red[4][16][16];
#pragma unroll
  for (int r = 0; r < 4; ++r) red[w][q * 4 + r][mi] = acc[r];
  __syncthreads();
  {
    const int orow = t >> 4, ocol = t & 15;
    const float s = red[0][orow][ocol] + red[1][orow][ocol] +
                    red[2][orow][ocol] + red[3][orow][ocol];
    m[(size_t)(r0 + orow) * NDIM + c0 + ocol] = s;
  }
}

// ---------------------------------------------------------------------------
// Kernel 2 (k_dist): verbatim R5 (harness-proven incl. graph tripwires).
// feats[i,k] += sum_j exp(-L1). B-slice staged in LDS, uniform broadcast
// reads, LDS-reduce -> atomicAdd (feats zeroed by k_prep).
// ---------------------------------------------------------------------------
__global__ __launch_bounds__(256) void k_dist(
    const float* __restrict__ m, float* __restrict__ out) {
  __shared__ float Bs[128 * DD];  // 8 KB
  __shared__ float red[256];
  const int t   = threadIdx.x;
  const int bid = blockIdx.x;
  const int ig  = bid >> 7;         // 0..7
  const int k   = (bid >> 2) & 31;  // 0..31
  const int jq  = bid & 3;          // j quarter
  const int lane = t & 63;
  const int i    = ig * 64 + lane;

  const float4* ap = (const float4*)(m + (size_t)i * NDIM + k * DD);
  const float4 A0 = ap[0], A1 = ap[1], A2 = ap[2], A3 = ap[3];

  const float* mb = m + (size_t)(jq * 128) * NDIM + k * DD;
#pragma unroll
  for (int qq = 0; qq < 2; ++qq) {
    const int idx = qq * 256 + t;        // 0..511
    const int jrow = idx >> 2, part = idx & 3;
    *(float4*)&Bs[jrow * DD + part * 4] =
        *(const float4*)(mb + (size_t)jrow * NDIM + part * 4);
  }
  __syncthreads();

  float a[DD];
  a[0]=A0.x; a[1]=A0.y; a[2]=A0.z;  a[3]=A0.w;
  a[4]=A1.x; a[5]=A1.y; a[6]=A1.z;  a[7]=A1.w;
  a[8]=A2.x; a[9]=A2.y; a[10]=A2.z; a[11]=A2.w;
  a[12]=A3.x;a[13]=A3.y;a[14]=A3.z; a[15]=A3.w;

  const int w = __builtin_amdgcn_readfirstlane(t >> 6);  // wave 0..3
  const int jbase = w * 32;
  float f = 0.f;
#pragma unroll 4
  for (int j = 0; j < 32; ++j) {
    const float4* bp = (const float4*)&Bs[(jbase + j) * DD];  // uniform
    const float4 b0 = bp[0], b1 = bp[1], b2 = bp[2], b3 = bp[3];
    float d =
        fabsf(a[0]  - b0.x) + fabsf(a[1]  - b0.y) +
        fabsf(a[2]  - b0.z) + fabsf(a[3]  - b0.w) +
        fabsf(a[4]  - b1.x) + fabsf(a[5]  - b1.y) +
        fabsf(a[6]  - b1.z) + fabsf(a[7]  - b1.w) +
        fabsf(a[8]  - b2.x) + fabsf(a[9]  - b2.y) +
        fabsf(a[10] - b2.z) + fabsf(a[11] - b2.w) +
        fabsf(a[12] - b3.x) + fabsf(a[13] - b3.y) +
        fabsf(a[14] - b3.z) + fabsf(a[15] - b3.w);
    f += __expf(-d);
  }

  red[t] = f;
  __syncthreads();
  if (t < 64) {
    const float s = red[t] + red[t + 64] + red[t + 128] + red[t + 192];
    atomicAdd(out + (size_t)(ig * 64 + t) * OUTW + FDIM + k, s);
  }
}

extern "C" void kernel_launch(void* const* d_in, const int* in_sizes, int n_in,
                              void* d_out, int out_size, void* d_ws,
                              size_t ws_size, hipStream_t stream) {
  (void)in_sizes; (void)n_in; (void)out_size; (void)ws_size;
  const float* x = (const float*)d_in[0];
  const float* T = (const float*)d_in[1];
  float* out = (float*)d_out;
  float* m = (float*)d_ws;                                   // 1 MB fp32
  unsigned short* xbf = (unsigned short*)((char*)d_ws + (size_t)BSZ * NDIM * 4);
  unsigned short* tbf = xbf + (size_t)BSZ * FDIM;            // +512 KB each

  hipLaunchKernelGGL(k_prep, dim3(128), dim3(256), 0, stream,
                     x, T, xbf, tbf, out);
  hipLaunchKernelGGL(k_gemm, dim3(1024), dim3(256), 0, stream, xbf, tbf, m);
  hipLaunchKernelGGL(k_dist, dim3(1024), dim3(256), 0, stream, m, out);
}